// Round 9
// baseline (197.371 us; speedup 1.0000x reference)
//
#include <hip/hip_runtime.h>
#include <math.h>

typedef __bf16 bf16x8 __attribute__((ext_vector_type(8)));
typedef __bf16 bf16x4 __attribute__((ext_vector_type(4)));
typedef float  f32x4  __attribute__((ext_vector_type(4)));

namespace {
constexpr int L_ = 512, D_ = 512, NF = 11;
constexpr long WE = (long)L_ * L_;   // 262144 elems, one 512x512 plane
constexpr long NE = 8 * WE;          // 2097152 elems, B*L*D
constexpr long CPL = 512L * 1024;    // concatenated plane (512 rows x 1024)
constexpr float NEGV = -1.0e9f;
constexpr float INV_TEMP = 0.044194173824159216f; // 1/sqrt(512)
}

typedef __attribute__((address_space(1))) void gv_t;
typedef __attribute__((address_space(3))) void lv_t;

__device__ __forceinline__ void async_cp16(const void* g, void* l) {
  __builtin_amdgcn_global_load_lds((gv_t*)g, (lv_t*)l, 16, 0, 0);
}

__device__ __forceinline__ bf16x8 cvt2(float4 a0, float4 a1) {
  bf16x8 f;
  f[0] = (__bf16)a0.x; f[1] = (__bf16)a0.y; f[2] = (__bf16)a0.z; f[3] = (__bf16)a0.w;
  f[4] = (__bf16)a1.x; f[5] = (__bf16)a1.y; f[6] = (__bf16)a1.z; f[7] = (__bf16)a1.w;
  return f;
}

// ======== NT GEMM core A: BM x BN, BK=64, counted-vmcnt (T3+T4), bf16 ========
// (R4/R8-proven, unchanged.) Used by scores/av2 (64x64).
template<int BM, int BN>
__device__ __forceinline__ void nt_db(const __bf16* __restrict__ A,
                                      const __bf16* __restrict__ B,
                                      const int K, const int m0, const int n0,
                                      char* smem, f32x4 (&acc)[BM / 32][BN / 32])
{
  constexpr int MI = BM / 32, NJ = BN / 32;
  constexpr int LOADS = MI + NJ;
  constexpr int ABUF = BM * 64;
  constexpr int BBUF = BN * 64;
  __bf16* sA = (__bf16*)smem;
  __bf16* sB = sA + 2 * ABUF;
  const int tid = threadIdx.x;
  const int w = tid >> 6, l = tid & 63;
  const int quad = l >> 4, l16 = l & 15;
  const int wm = (w >> 1) * (BM / 2), wn = (w & 1) * (BN / 2);
  const int lr = l >> 3;
  const int sc = ((l & 7) ^ lr) << 3;
  const __bf16* gA = A + (long)(m0 + lr) * K + sc;
  const __bf16* gB = B + (long)(n0 + lr) * K + sc;
  const int xo = (l16 & 7) << 4;

  auto stage = [&](int buf, int k0) {
    char* dA = (char*)(sA + buf * ABUF) + l * 16;
    char* dB = (char*)(sB + buf * BBUF) + l * 16;
    #pragma unroll
    for (int ci = 0; ci < MI; ++ci) {
      const int qi = ci * 4 + w;
      async_cp16(gA + (long)(qi * 8) * K + k0, dA + qi * 1024);
    }
    #pragma unroll
    for (int ci = 0; ci < NJ; ++ci) {
      const int qi = ci * 4 + w;
      async_cp16(gB + (long)(qi * 8) * K + k0, dB + qi * 1024);
    }
  };
  auto compute = [&](int buf) {
    const char* bA = (const char*)(sA + buf * ABUF);
    const char* bB = (const char*)(sB + buf * BBUF);
    #pragma unroll
    for (int p = 0; p < 2; ++p) {
      bf16x8 af[MI], bfr[NJ];
      #pragma unroll
      for (int i = 0; i < MI; ++i)
        af[i] = *(const bf16x8*)(bA + (wm + i * 16 + l16) * 128
                                 + ((p * 64 + quad * 16) ^ xo));
      #pragma unroll
      for (int j = 0; j < NJ; ++j)
        bfr[j] = *(const bf16x8*)(bB + (wn + j * 16 + l16) * 128
                                  + ((p * 64 + quad * 16) ^ xo));
      __builtin_amdgcn_s_setprio(1);
      #pragma unroll
      for (int i = 0; i < MI; ++i)
        #pragma unroll
        for (int j = 0; j < NJ; ++j)
          acc[i][j] = __builtin_amdgcn_mfma_f32_16x16x32_bf16(af[i], bfr[j], acc[i][j], 0, 0, 0);
      __builtin_amdgcn_s_setprio(0);
    }
  };

  stage(0, 0);
  int cur = 0;
  const int NS = K >> 6;
  for (int s = 0; s < NS; ++s) {
    if (s + 1 < NS) {
      stage(cur ^ 1, (s + 1) << 6);
      asm volatile("s_waitcnt vmcnt(%0)" :: "n"(LOADS) : "memory");
    } else {
      asm volatile("s_waitcnt vmcnt(0)" ::: "memory");
    }
    __builtin_amdgcn_sched_barrier(0);
    __builtin_amdgcn_s_barrier();
    compute(cur);
    __builtin_amdgcn_s_barrier();
    cur ^= 1;
  }
  __builtin_amdgcn_sched_barrier(0);
}

// ======== NT GEMM core B: BM x BN, BK=32, mixed fp32/bf16 operands ===========
// LDS always bf16 [rows][32] (64B rows, 16B slots XOR-swizzled by row&3).
// bf16 operand: global_load_lds direct (source col pre-swizzled).
// fp32 operand: reg-staged (2x float4 -> v_cvt -> ds_write_b128, same layout)
// -> fp32->bf16 rounding happens here, identical to a separate cvt pass.
// Schedule/iter: issue(next) ; MFMA(cur) ; vmcnt(0) [hidden under MFMA] ;
// ds_write(next) ; lgkmcnt(0) ; ONE s_barrier.
template<int BM, int BN, bool AF32, bool BF32>
__device__ __forceinline__ void nt32(const void* Av, const void* Bv,
                                     const int K, const int m0, const int n0,
                                     char* smem, f32x4 (&acc)[BM / 32][BN / 32])
{
  constexpr int MI = BM / 32, NJ = BN / 32;
  constexpr int AC = BM / 64, BC = BN / 64;   // 1024B chunks per wave
  constexpr int ABUF = BM * 32, BBUF = BN * 32;
  __bf16* sA = (__bf16*)smem;
  __bf16* sB = sA + 2 * ABUF;
  const int tid = threadIdx.x;
  const int w = tid >> 6, l = tid & 63;
  const int quad = l >> 4, l16 = l & 15;
  const int wm = (w >> 1) * (BM / 2), wn = (w & 1) * (BN / 2);
  const int lr = l >> 2;                      // row within 16-row chunk
  const int sc = (((l & 3) ^ (lr & 3)) << 3); // swizzled source col (elems)
  const __bf16* gAb = (const __bf16*)Av + (long)(m0 + lr) * K + sc;
  const __bf16* gBb = (const __bf16*)Bv + (long)(n0 + lr) * K + sc;
  const float*  gAf = (const float*)Av  + (long)(m0 + lr) * K + sc;
  const float*  gBf = (const float*)Bv  + (long)(n0 + lr) * K + sc;
  const int xo = (l16 & 3) << 4;              // read-side XOR (bytes)

  float4 fa[AC][2], fb[BC][2];

  auto issue = [&](int buf, int k0) {
    char* dA = (char*)(sA + buf * ABUF) + l * 16;
    char* dB = (char*)(sB + buf * BBUF) + l * 16;
    #pragma unroll
    for (int ci = 0; ci < AC; ++ci) {
      const int qi = ci * 4 + w;
      if constexpr (AF32) {
        const float* p = gAf + (long)(qi * 16) * K + k0;
        fa[ci][0] = *(const float4*)(p);
        fa[ci][1] = *(const float4*)(p + 4);
      } else {
        async_cp16(gAb + (long)(qi * 16) * K + k0, dA + qi * 1024);
      }
    }
    #pragma unroll
    for (int ci = 0; ci < BC; ++ci) {
      const int qi = ci * 4 + w;
      if constexpr (BF32) {
        const float* p = gBf + (long)(qi * 16) * K + k0;
        fb[ci][0] = *(const float4*)(p);
        fb[ci][1] = *(const float4*)(p + 4);
      } else {
        async_cp16(gBb + (long)(qi * 16) * K + k0, dB + qi * 1024);
      }
    }
  };
  auto write_regs = [&](int buf) {
    char* dA = (char*)(sA + buf * ABUF) + l * 16;
    char* dB = (char*)(sB + buf * BBUF) + l * 16;
    if constexpr (AF32) {
      #pragma unroll
      for (int ci = 0; ci < AC; ++ci)
        *(bf16x8*)(dA + (ci * 4 + w) * 1024) = cvt2(fa[ci][0], fa[ci][1]);
    }
    if constexpr (BF32) {
      #pragma unroll
      for (int ci = 0; ci < BC; ++ci)
        *(bf16x8*)(dB + (ci * 4 + w) * 1024) = cvt2(fb[ci][0], fb[ci][1]);
    }
  };
  auto compute = [&](int buf) {
    const char* bA = (const char*)(sA + buf * ABUF);
    const char* bB = (const char*)(sB + buf * BBUF);
    bf16x8 af[MI], bfr[NJ];
    #pragma unroll
    for (int i = 0; i < MI; ++i)
      af[i] = *(const bf16x8*)(bA + (wm + i * 16 + l16) * 64 + ((quad * 16) ^ xo));
    #pragma unroll
    for (int j = 0; j < NJ; ++j)
      bfr[j] = *(const bf16x8*)(bB + (wn + j * 16 + l16) * 64 + ((quad * 16) ^ xo));
    __builtin_amdgcn_s_setprio(1);
    #pragma unroll
    for (int i = 0; i < MI; ++i)
      #pragma unroll
      for (int j = 0; j < NJ; ++j)
        acc[i][j] = __builtin_amdgcn_mfma_f32_16x16x32_bf16(af[i], bfr[j], acc[i][j], 0, 0, 0);
    __builtin_amdgcn_s_setprio(0);
  };

  issue(0, 0);
  asm volatile("s_waitcnt vmcnt(0)" ::: "memory");
  write_regs(0);
  __syncthreads();
  int cur = 0;
  const int NS = K >> 5;
  for (int s = 0; s < NS; ++s) {
    const bool more = (s + 1 < NS);
    if (more) issue(cur ^ 1, (s + 1) << 5);   // loads/gl_lds in flight
    compute(cur);                             // full MFMA phase hides latency
    if (more) {
      asm volatile("s_waitcnt vmcnt(0)" ::: "memory");  // staging landed
      __builtin_amdgcn_sched_barrier(0);
      write_regs(cur ^ 1);                    // fp32 operands -> LDS
    }
    asm volatile("s_waitcnt lgkmcnt(0)" ::: "memory");
    __builtin_amdgcn_sched_barrier(0);
    __builtin_amdgcn_s_barrier();             // next buf published; cur free
    cur ^= 1;
  }
  __builtin_amdgcn_sched_barrier(0);
}

// ======== k1: 5 projections fp32-direct (fid<640) + feature softmax ==========
__global__ __launch_bounds__(256)
void projfeat_kernel(const float* __restrict__ q, const float* __restrict__ k,
                     const float* __restrict__ v,
                     const float* __restrict__ Wq, const float* __restrict__ Wk,
                     const float* __restrict__ Wqf, const float* __restrict__ Wkf,
                     const float* __restrict__ Wv,
                     const float* __restrict__ x, const float* __restrict__ imp,
                     const int* __restrict__ lens,
                     __bf16* __restrict__ qcat, __bf16* __restrict__ kcat,
                     __bf16* __restrict__ qfkfT, __bf16* __restrict__ vpb,
                     __bf16* __restrict__ featb)
{
  __shared__ __align__(16) char smem[32768];  // 32 KB
  const int fid = blockIdx.x;
  const int tid = threadIdx.x;
  const int w = tid >> 6, l = tid & 63;

  if (fid < 640) {
    const int xcd = fid & 7, g = fid >> 3;    // 640 = 8 * 80
    const int z = g >> 4, r = g & 15;         // z: 0 Wq, 1 Wk, 2 Wqf, 3 Wkf, 4 Wv
    const int n0 = (r & 3) * 128;
    const int m0 = (((r >> 2) << 3) + xcd) * 128;
    const float* As[5] = {q, k, q, k, v};
    const float* Bs[5] = {Wq, Wk, Wqf, Wkf, Wv};
    f32x4 acc[4][4];
    #pragma unroll
    for (int i = 0; i < 4; ++i)
      #pragma unroll
      for (int j = 0; j < 4; ++j) acc[i][j] = 0.0f;
    nt32<128, 128, true, true>(As[z], Bs[z], 512, m0, n0, smem, acc);

    const int quad = l >> 4, l16 = l & 15;
    const int wm = (w >> 1) * 64, wn = (w & 1) * 64;
    #pragma unroll
    for (int i = 0; i < 4; ++i) {
      const int mb = m0 + wm + i * 16 + quad * 4;
      #pragma unroll
      for (int j = 0; j < 4; ++j) {
        const int nn = n0 + wn + j * 16 + l16;
        f32x4 c = acc[i][j];
        if (z < 2) {
          __bf16* C = (z == 0) ? qcat : kcat;
          #pragma unroll
          for (int r2 = 0; r2 < 4; ++r2)
            C[(long)(mb + r2) * 1024 + nn] = (__bf16)c[r2];
        } else if (z == 4) {
          #pragma unroll
          for (int r2 = 0; r2 < 4; ++r2)
            vpb[(long)(mb + r2) * 512 + nn] = (__bf16)c[r2];
        } else {                               // qf/kf written transposed
          __bf16* T = qfkfT + (long)(z - 2) * NE;
          const long bb = (long)(mb >> 9) << 18;
          const int li = mb & 511;
          bf16x4 pk;
          pk[0] = (__bf16)c[0]; pk[1] = (__bf16)c[1];
          pk[2] = (__bf16)c[2]; pk[3] = (__bf16)c[3];
          *(bf16x4*)(T + bb + (long)nn * 512 + li) = pk;
        }
      }
    }
    return;
  }

  // ---- feature softmax (proven path), blocks 640..767 ----
  float* xfs = (float*)smem;                  // 22.5 KB
  const int flat = fid - 640;
  const int b = flat >> 4;
  const int i0 = (flat & 15) * 32;
  for (int idx = tid; idx < L_ * NF; idx += 256) {
    int j = idx / NF, f = idx - j * NF;
    xfs[idx] = x[((long)b * L_ + j) * D_ + f];
  }
  float im[NF];
  #pragma unroll
  for (int f = 0; f < NF; ++f) im[f] = imp[f];
  const int len = lens[b];
  __syncthreads();
  for (int r = 0; r < 8; ++r) {
    const int i = i0 + w * 8 + r;
    float xi[NF];
    #pragma unroll
    for (int f = 0; f < NF; ++f) xi[f] = xfs[i * NF + f];
    float lv[8];
    float m = -INFINITY;
    #pragma unroll
    for (int t = 0; t < 8; ++t) {
      int j = l + t * 64;
      float s = 0.f;
      #pragma unroll
      for (int f = 0; f < NF; ++f) s = fmaf(fabsf(xi[f] - xfs[j * NF + f]), im[f], s);
      s = (j < len) ? s : NEGV;
      lv[t] = s;
      m = fmaxf(m, s);
    }
    #pragma unroll
    for (int o = 32; o >= 1; o >>= 1) m = fmaxf(m, __shfl_xor(m, o));
    float ssum = 0.f;
    #pragma unroll
    for (int t = 0; t < 8; ++t) { lv[t] = expf(lv[t] - m); ssum += lv[t]; }
    #pragma unroll
    for (int o = 32; o >= 1; o >>= 1) ssum += __shfl_xor(ssum, o);
    float inv = 1.0f / ssum;
    #pragma unroll
    for (int t = 0; t < 8; ++t)
      featb[((long)b * L_ + i) * L_ + l + t * 64] = (__bf16)(lv[t] * inv);
  }
}

// ======== k2: qf2 -> qcat[:,512:], kf2 -> kcat[:,512:], vp2T (384 blocks) ====
__global__ __launch_bounds__(256)
void mega2_kernel(const __bf16* __restrict__ featb, const __bf16* __restrict__ qfkfT,
                  const float* __restrict__ Wfc, const __bf16* __restrict__ vpb,
                  __bf16* __restrict__ qcat, __bf16* __restrict__ kcat,
                  __bf16* __restrict__ vp2T)
{
  __shared__ __align__(16) char smem[32768];
  const int id = blockIdx.x;
  const int xcd = id & 7, g = id >> 3;        // 384 = 8 * 48
  const int z = g >> 1;                       // 0..23
  const int t = (g & 1) * 8 + xcd;            // tile 0..15
  const int m0 = (t >> 2) * 128, n0 = (t & 3) * 128;
  f32x4 acc[4][4];
  #pragma unroll
  for (int i = 0; i < 4; ++i)
    #pragma unroll
    for (int j = 0; j < 4; ++j) acc[i][j] = 0.0f;

  __bf16* C;
  int ldc;
  if (z < 16) {
    const int b = z & 7, s = z >> 3;
    const __bf16* A = featb + (long)b * WE;
    const __bf16* B = qfkfT + (long)s * NE + (long)b * WE;
    C = (s ? kcat : qcat) + (long)b * CPL + 512;
    ldc = 1024;
    nt32<128, 128, false, false>(A, B, 512, m0, n0, smem, acc);
  } else {
    const int b = z - 16;
    const __bf16* B = vpb + (long)b * WE;
    C = vp2T + (long)b * WE;
    ldc = 512;
    nt32<128, 128, true, false>(Wfc, B, 512, m0, n0, smem, acc);
  }

  const int tid = threadIdx.x, w = tid >> 6, l = tid & 63;
  const int quad = l >> 4, l16 = l & 15;
  const int wm = (w >> 1) * 64, wn = (w & 1) * 64;
  #pragma unroll
  for (int i = 0; i < 4; ++i) {
    const int mb = m0 + wm + i * 16 + quad * 4;
    #pragma unroll
    for (int j = 0; j < 4; ++j) {
      const int nn = n0 + wn + j * 16 + l16;
      f32x4 c = acc[i][j];
      #pragma unroll
      for (int r2 = 0; r2 < 4; ++r2)
        C[(long)(mb + r2) * ldc + nn] = (__bf16)c[r2];
    }
  }
}

// ======== k3: attn = tanh(mask(qcat.kcat^T/temp)), 64x64 tiles, 512 blocks ===
__global__ __launch_bounds__(256)
void scores_kernel(const __bf16* __restrict__ qcat, const __bf16* __restrict__ kcat,
                   const int* __restrict__ lens, float* __restrict__ attnf,
                   __bf16* __restrict__ attnb)
{
  __shared__ __align__(16) char smem[32768];
  const int id = blockIdx.x;                  // 512 = 8 b * 64 tiles
  const int b = id & 7, g = id >> 3;          // one b per XCD -> L2-resident
  const int m0 = (g >> 3) * 64, n0 = (g & 7) * 64;
  const int len = lens[b];
  f32x4 acc[2][2];
  #pragma unroll
  for (int i = 0; i < 2; ++i)
    #pragma unroll
    for (int j = 0; j < 2; ++j) acc[i][j] = 0.0f;
  nt_db<64, 64>(qcat + (long)b * CPL, kcat + (long)b * CPL, 1024, m0, n0, smem, acc);

  const long off = (long)b * WE;
  const int tid = threadIdx.x, w = tid >> 6, l = tid & 63;
  const int quad = l >> 4, l16 = l & 15;
  const int wm = (w >> 1) * 32, wn = (w & 1) * 32;
  #pragma unroll
  for (int i = 0; i < 2; ++i) {
    const int mb = m0 + wm + i * 16 + quad * 4;
    #pragma unroll
    for (int j = 0; j < 2; ++j) {
      const int nn = n0 + wn + j * 16 + l16;
      f32x4 c = acc[i][j];
      #pragma unroll
      for (int r2 = 0; r2 < 4; ++r2) {
        float vv = c[r2] * INV_TEMP;
        vv = (nn < len) ? tanhf(vv) : 0.0f;
        attnf[off + (long)(mb + r2) * 512 + nn] = vv;
        attnb[off + (long)(mb + r2) * 512 + nn] = (__bf16)vv;
      }
    }
  }
}

// ======== k4: u = attn @ vp2 + q (residual), 64x64 tiles, 512 blocks ========
__global__ __launch_bounds__(256)
void av2_kernel(const __bf16* __restrict__ attnb, const __bf16* __restrict__ vp2T,
                const float* __restrict__ q, float* __restrict__ outp)
{
  __shared__ __align__(16) char smem[32768];
  const int id = blockIdx.x;
  const int b = id & 7, g = id >> 3;
  const int m0 = (g >> 3) * 64, n0 = (g & 7) * 64;
  f32x4 acc[2][2];
  #pragma unroll
  for (int i = 0; i < 2; ++i)
    #pragma unroll
    for (int j = 0; j < 2; ++j) acc[i][j] = 0.0f;
  nt_db<64, 64>(attnb + (long)b * WE, vp2T + (long)b * WE, 512, m0, n0, smem, acc);

  const int tid = threadIdx.x, w = tid >> 6, l = tid & 63;
  const int quad = l >> 4, l16 = l & 15;
  const int wm = (w >> 1) * 32, wn = (w & 1) * 32;
  #pragma unroll
  for (int i = 0; i < 2; ++i) {
    const int mb = m0 + wm + i * 16 + quad * 4;
    #pragma unroll
    for (int j = 0; j < 2; ++j) {
      const int nn = n0 + wn + j * 16 + l16;
      f32x4 c = acc[i][j];
      #pragma unroll
      for (int r2 = 0; r2 < 4; ++r2) {
        const long row = (long)b * 512 + mb + r2;
        outp[row * 512 + nn] = c[r2] + q[row * 512 + nn];
      }
    }
  }
}

// ======== k5: in-place row LayerNorm (1 wave per row) ========
__global__ __launch_bounds__(256)
void ln_kernel(float* __restrict__ o, const float* __restrict__ gamma,
               const float* __restrict__ beta)
{
  const int w = threadIdx.x >> 6, l = threadIdx.x & 63;
  float* p = o + ((long)blockIdx.x * 4 + w) * 512;
  const float4 a = ((const float4*)p)[l * 2];
  const float4 c = ((const float4*)p)[l * 2 + 1];
  float s  = a.x + a.y + a.z + a.w + c.x + c.y + c.z + c.w;
  float ss = a.x * a.x + a.y * a.y + a.z * a.z + a.w * a.w
           + c.x * c.x + c.y * c.y + c.z * c.z + c.w * c.w;
  #pragma unroll
  for (int o2 = 32; o2 >= 1; o2 >>= 1) { s += __shfl_xor(s, o2); ss += __shfl_xor(ss, o2); }
  const float mu = s * (1.0f / 512.0f);
  const float var = ss * (1.0f / 512.0f) - mu * mu;
  const float inv = 1.0f / sqrtf(var + 1e-6f);
  const float4 g0 = ((const float4*)gamma)[l * 2], g1 = ((const float4*)gamma)[l * 2 + 1];
  const float4 b0 = ((const float4*)beta)[l * 2],  b1 = ((const float4*)beta)[l * 2 + 1];
  float4 r0, r1;
  r0.x = (a.x - mu) * inv * g0.x + b0.x;
  r0.y = (a.y - mu) * inv * g0.y + b0.y;
  r0.z = (a.z - mu) * inv * g0.z + b0.z;
  r0.w = (a.w - mu) * inv * g0.w + b0.w;
  r1.x = (c.x - mu) * inv * g1.x + b1.x;
  r1.y = (c.y - mu) * inv * g1.y + b1.y;
  r1.z = (c.z - mu) * inv * g1.z + b1.z;
  r1.w = (c.w - mu) * inv * g1.w + b1.w;
  ((float4*)p)[l * 2] = r0;
  ((float4*)p)[l * 2 + 1] = r1;
}

extern "C" void kernel_launch(void* const* d_in, const int* in_sizes, int n_in,
                              void* d_out, int out_size, void* d_ws, size_t ws_size,
                              hipStream_t stream) {
    const float* q     = (const float*)d_in[0];
    const float* k     = (const float*)d_in[1];
    const float* v     = (const float*)d_in[2];
    const float* x     = (const float*)d_in[3];
    const int*   lens  = (const int*)d_in[4];
    const float* Wq    = (const float*)d_in[5];
    const float* Wk    = (const float*)d_in[6];
    const float* Wv    = (const float*)d_in[7];
    const float* Wqf   = (const float*)d_in[8];
    const float* Wkf   = (const float*)d_in[9];
    const float* Wfc   = (const float*)d_in[10];
    const float* imp   = (const float*)d_in[11];
    const float* gamma = (const float*)d_in[12];
    const float* beta  = (const float*)d_in[13];

    constexpr long MB = 1 << 20;
    char* w = (char*)d_ws;
    __bf16* qfkfT = (__bf16*)(w);            //  0.. 8MB : qfT,kfT (transposed)
    __bf16* vpb   = (__bf16*)(w + 8 * MB);   //  8..12MB : vp
    __bf16* vp2T  = (__bf16*)(w + 12 * MB);  // 12..16MB : vp2T
    __bf16* qcat  = (__bf16*)(w + 16 * MB);  // 16..24MB : [qp | qf2] K=1024
    __bf16* kcat  = (__bf16*)(w + 24 * MB);  // 24..32MB : [kp | kf2]
    __bf16* featb = (__bf16*)(w + 32 * MB);  // 32..36MB : feat_attn bf16
    __bf16* attnb = (__bf16*)(w + 36 * MB);  // 36..40MB : attn bf16

    float*  outp  = (float*)d_out;           // output 0 [B,L,D]
    float*  attnf = outp + NE;               // output 1 [B,L,L]

    // 1) 5 projections fp32-direct (640) + feature softmax (128) = 768 blocks
    projfeat_kernel<<<dim3(768), 256, 0, stream>>>(q, k, v, Wq, Wk, Wqf, Wkf, Wv,
                                                   x, imp, lens,
                                                   qcat, kcat, qfkfT, vpb, featb);

    // 2) qf2,kf2 -> cat right halves + vp2T = NT(Wfc, vp) (384 blocks)
    mega2_kernel<<<dim3(384), 256, 0, stream>>>(featb, qfkfT, Wfc, vpb,
                                                qcat, kcat, vp2T);

    // 3) attn = tanh(mask(qcat.kcat^T / temp)), K=1024 (512 blocks, 64x64)
    scores_kernel<<<dim3(512), 256, 0, stream>>>(qcat, kcat, lens, attnf, attnb);

    // 4) u = attn @ vp2 + residual (512 blocks, 64x64)
    av2_kernel<<<dim3(512), 256, 0, stream>>>(attnb, vp2T, q, outp);

    // 5) in-place LayerNorm (1024 blocks, 1 wave/row)
    ln_kernel<<<dim3(1024), 256, 0, stream>>>(outp, gamma, beta);
}

// Round 10
// 167.445 us; speedup vs baseline: 1.1787x; 1.1787x over previous
//
#include <hip/hip_runtime.h>
#include <math.h>

typedef __bf16 bf16x8 __attribute__((ext_vector_type(8)));
typedef __bf16 bf16x4 __attribute__((ext_vector_type(4)));
typedef float  f32x4  __attribute__((ext_vector_type(4)));

namespace {
constexpr int L_ = 512, D_ = 512, NF = 11;
constexpr long WE = (long)L_ * L_;   // 262144 elems, one 512x512 plane
constexpr long NE = 8 * WE;          // 2097152 elems, B*L*D
constexpr long CPL = 512L * 1024;    // concatenated plane (512 rows x 1024)
constexpr float NEGV = -1.0e9f;
constexpr float INV_TEMP = 0.044194173824159216f; // 1/sqrt(512)
}

typedef __attribute__((address_space(1))) void gv_t;
typedef __attribute__((address_space(3))) void lv_t;

__device__ __forceinline__ void async_cp16(const void* g, void* l) {
  __builtin_amdgcn_global_load_lds((gv_t*)g, (lv_t*)l, 16, 0, 0);
}

// ======== NT GEMM core: BM x BN tile, BK=64, counted-vmcnt pipeline (T3+T4) ==
// LDS per buffer: [rows][64] bf16 (128B rows), 16B slots XOR-swizzled by
// (row&7); global_load_lds dest lane-linear, source col pre-swizzled, read
// applies same XOR -> conflict-free ds_read_b128.
// Schedule per K-step (raw s_barrier, NO vmcnt(0) drain in main loop):
//   stage(next); s_waitcnt vmcnt(LOADS) // waits only PREV step's loads
//   s_barrier ; MFMA(cur) ; s_barrier
template<int BM, int BN>
__device__ __forceinline__ void nt_db(const __bf16* __restrict__ A,
                                      const __bf16* __restrict__ B,
                                      const int K, const int m0, const int n0,
                                      char* smem, f32x4 (&acc)[BM / 32][BN / 32])
{
  constexpr int MI = BM / 32, NJ = BN / 32;
  constexpr int LOADS = MI + NJ;              // per-thread loads per stage
  constexpr int ABUF = BM * 64;
  constexpr int BBUF = BN * 64;
  __bf16* sA = (__bf16*)smem;
  __bf16* sB = sA + 2 * ABUF;
  const int tid = threadIdx.x;
  const int w = tid >> 6, l = tid & 63;
  const int quad = l >> 4, l16 = l & 15;
  const int wm = (w >> 1) * (BM / 2), wn = (w & 1) * (BN / 2);
  const int lr = l >> 3;                      // row within 8-row chunk
  const int sc = ((l & 7) ^ lr) << 3;         // swizzled source col (elems)
  const __bf16* gA = A + (long)(m0 + lr) * K + sc;
  const __bf16* gB = B + (long)(n0 + lr) * K + sc;
  const int xo = (l16 & 7) << 4;              // read-side XOR (bytes)

  auto stage = [&](int buf, int k0) {
    char* dA = (char*)(sA + buf * ABUF) + l * 16;
    char* dB = (char*)(sB + buf * BBUF) + l * 16;
    #pragma unroll
    for (int ci = 0; ci < MI; ++ci) {
      const int qi = ci * 4 + w;
      async_cp16(gA + (long)(qi * 8) * K + k0, dA + qi * 1024);
    }
    #pragma unroll
    for (int ci = 0; ci < NJ; ++ci) {
      const int qi = ci * 4 + w;
      async_cp16(gB + (long)(qi * 8) * K + k0, dB + qi * 1024);
    }
  };
  auto compute = [&](int buf) {
    const char* bA = (const char*)(sA + buf * ABUF);
    const char* bB = (const char*)(sB + buf * BBUF);
    #pragma unroll
    for (int p = 0; p < 2; ++p) {
      bf16x8 af[MI], bfr[NJ];
      #pragma unroll
      for (int i = 0; i < MI; ++i)
        af[i] = *(const bf16x8*)(bA + (wm + i * 16 + l16) * 128
                                 + ((p * 64 + quad * 16) ^ xo));
      #pragma unroll
      for (int j = 0; j < NJ; ++j)
        bfr[j] = *(const bf16x8*)(bB + (wn + j * 16 + l16) * 128
                                  + ((p * 64 + quad * 16) ^ xo));
      __builtin_amdgcn_s_setprio(1);
      #pragma unroll
      for (int i = 0; i < MI; ++i)
        #pragma unroll
        for (int j = 0; j < NJ; ++j)
          acc[i][j] = __builtin_amdgcn_mfma_f32_16x16x32_bf16(af[i], bfr[j], acc[i][j], 0, 0, 0);
      __builtin_amdgcn_s_setprio(0);
    }
  };

  stage(0, 0);
  int cur = 0;
  const int NS = K >> 6;
  for (int s = 0; s < NS; ++s) {
    if (s + 1 < NS) {
      stage(cur ^ 1, (s + 1) << 6);
      asm volatile("s_waitcnt vmcnt(%0)" :: "n"(LOADS) : "memory");
    } else {
      asm volatile("s_waitcnt vmcnt(0)" ::: "memory");
    }
    __builtin_amdgcn_sched_barrier(0);
    __builtin_amdgcn_s_barrier();             // cur buffer fully staged
    compute(cur);
    __builtin_amdgcn_s_barrier();             // all reads of cur done
    cur ^= 1;
  }
  __builtin_amdgcn_sched_barrier(0);          // keep epilogue below barriers
}

// ======== k1: bf16 conversion (q,k,v + 6 weights) + feature softmax ========
__global__ __launch_bounds__(256)
void cvtfeat_kernel(const float* __restrict__ q, const float* __restrict__ k,
                    const float* __restrict__ v, const float* __restrict__ x,
                    const float* __restrict__ imp, const int* __restrict__ lens,
                    const float* __restrict__ Wq, const float* __restrict__ Wk,
                    const float* __restrict__ Wqf, const float* __restrict__ Wkf,
                    const float* __restrict__ Wv, const float* __restrict__ Wfc,
                    __bf16* __restrict__ qb, __bf16* __restrict__ kb,
                    __bf16* __restrict__ vb, __bf16* __restrict__ wb,
                    __bf16* __restrict__ featb)
{
  __shared__ float xfs[L_ * NF];              // 22.5 KB (feat path only)
  const int fid = blockIdx.x;
  const int tid = threadIdx.x;

  if (fid >= 128) {
    constexpr long QC8 = 262144;              // 8-elem granules per q/k/v (2^18)
    constexpr long WC8 = 32768;               // granules per weight (2^15)
    constexpr long TOT8 = 3 * QC8 + 6 * WC8;  // 983040
    const float* srcs[9] = {q, k, v, Wq, Wk, Wqf, Wkf, Wv, Wfc};
    __bf16* dsts[9] = {qb, kb, vb, wb, wb + WE, wb + 2 * WE,
                       wb + 3 * WE, wb + 4 * WE, wb + 5 * WE};
    for (long t = (long)(fid - 128) * 256 + tid; t < TOT8; t += 896L * 256) {
      int ti; long off;
      if (t < 3 * QC8) { ti = (int)(t >> 18); off = t & (QC8 - 1); }
      else { long u = t - 3 * QC8; ti = 3 + (int)(u >> 15); off = u & (WC8 - 1); }
      const float4 f0 = ((const float4*)srcs[ti])[off * 2];
      const float4 f1 = ((const float4*)srcs[ti])[off * 2 + 1];
      bf16x8 o;
      o[0] = (__bf16)f0.x; o[1] = (__bf16)f0.y; o[2] = (__bf16)f0.z; o[3] = (__bf16)f0.w;
      o[4] = (__bf16)f1.x; o[5] = (__bf16)f1.y; o[6] = (__bf16)f1.z; o[7] = (__bf16)f1.w;
      ((bf16x8*)dsts[ti])[off] = o;
    }
    return;
  }

  // ---- feature softmax (unchanged, proven) ----
  const int wave = tid >> 6, lane = tid & 63;
  const int b = fid >> 4;
  const int i0 = (fid & 15) * 32;
  for (int idx = tid; idx < L_ * NF; idx += 256) {
    int j = idx / NF, f = idx - j * NF;
    xfs[idx] = x[((long)b * L_ + j) * D_ + f];
  }
  float im[NF];
  #pragma unroll
  for (int f = 0; f < NF; ++f) im[f] = imp[f];
  const int len = lens[b];
  __syncthreads();
  for (int r = 0; r < 8; ++r) {
    const int i = i0 + wave * 8 + r;
    float xi[NF];
    #pragma unroll
    for (int f = 0; f < NF; ++f) xi[f] = xfs[i * NF + f];
    float lv[8];
    float m = -INFINITY;
    #pragma unroll
    for (int t = 0; t < 8; ++t) {
      int j = lane + t * 64;
      float s = 0.f;
      #pragma unroll
      for (int f = 0; f < NF; ++f) s = fmaf(fabsf(xi[f] - xfs[j * NF + f]), im[f], s);
      s = (j < len) ? s : NEGV;
      lv[t] = s;
      m = fmaxf(m, s);
    }
    #pragma unroll
    for (int o = 32; o >= 1; o >>= 1) m = fmaxf(m, __shfl_xor(m, o));
    float ssum = 0.f;
    #pragma unroll
    for (int t = 0; t < 8; ++t) { lv[t] = expf(lv[t] - m); ssum += lv[t]; }
    #pragma unroll
    for (int o = 32; o >= 1; o >>= 1) ssum += __shfl_xor(ssum, o);
    float inv = 1.0f / ssum;
    #pragma unroll
    for (int t = 0; t < 8; ++t)
      featb[((long)b * L_ + i) * L_ + lane + t * 64] = (__bf16)(lv[t] * inv);
  }
}

// ======== k2: 5 projections, 128x128 tiles, XCD-swizzled (640 blocks) ========
__global__ __launch_bounds__(256)
void proj_kernel(const __bf16* __restrict__ qb, const __bf16* __restrict__ kb,
                 const __bf16* __restrict__ vb, const __bf16* __restrict__ wb,
                 __bf16* __restrict__ qcat, __bf16* __restrict__ kcat,
                 __bf16* __restrict__ qfkfT, __bf16* __restrict__ vpb)
{
  __shared__ __align__(16) char smem[65536];  // 64 KB -> 2 blocks/CU
  const int fid = blockIdx.x;
  const int xcd = fid & 7, g = fid >> 3;      // 640 = 8 * 80
  const int z = g >> 4, r = g & 15;           // z: 0 Wq, 1 Wk, 2 Wqf, 3 Wkf, 4 Wv
  const int n0 = (r & 3) * 128;
  const int m0 = (((r >> 2) << 3) + xcd) * 128;  // same m-rows -> same XCD L2
  const __bf16* A = (z == 0 || z == 2) ? qb : (z == 4 ? vb : kb);
  const __bf16* B = wb + (long)z * WE;
  f32x4 acc[4][4];
  #pragma unroll
  for (int i = 0; i < 4; ++i)
    #pragma unroll
    for (int j = 0; j < 4; ++j) acc[i][j] = 0.0f;
  nt_db<128, 128>(A, B, 512, m0, n0, smem, acc);

  const int tid = threadIdx.x, w = tid >> 6, l = tid & 63;
  const int quad = l >> 4, l16 = l & 15;
  const int wm = (w >> 1) * 64, wn = (w & 1) * 64;
  #pragma unroll
  for (int i = 0; i < 4; ++i) {
    const int mb = m0 + wm + i * 16 + quad * 4;
    #pragma unroll
    for (int j = 0; j < 4; ++j) {
      const int nn = n0 + wn + j * 16 + l16;
      f32x4 c = acc[i][j];
      if (z < 2) {
        __bf16* C = (z == 0) ? qcat : kcat;
        #pragma unroll
        for (int r2 = 0; r2 < 4; ++r2)
          C[(long)(mb + r2) * 1024 + nn] = (__bf16)c[r2];
      } else if (z == 4) {
        #pragma unroll
        for (int r2 = 0; r2 < 4; ++r2)
          vpb[(long)(mb + r2) * 512 + nn] = (__bf16)c[r2];
      } else {                                 // qf/kf written transposed
        __bf16* T = qfkfT + (long)(z - 2) * NE;
        const long bb = (long)(mb >> 9) << 18;
        const int li = mb & 511;
        bf16x4 pk;
        pk[0] = (__bf16)c[0]; pk[1] = (__bf16)c[1];
        pk[2] = (__bf16)c[2]; pk[3] = (__bf16)c[3];
        *(bf16x4*)(T + bb + (long)nn * 512 + li) = pk;
      }
    }
  }
}

// ======== k3: qf2 -> qcat[:,512:], kf2 -> kcat[:,512:], vp2T (384 blocks) ====
__global__ __launch_bounds__(256)
void mega2_kernel(const __bf16* __restrict__ featb, const __bf16* __restrict__ qfkfT,
                  const __bf16* __restrict__ wb, const __bf16* __restrict__ vpb,
                  __bf16* __restrict__ qcat, __bf16* __restrict__ kcat,
                  __bf16* __restrict__ vp2T)
{
  __shared__ __align__(16) char smem[65536];
  const int id = blockIdx.x;
  const int xcd = id & 7, g = id >> 3;        // 384 = 8 * 48
  const int z = g >> 1;                       // 0..23
  const int t = (g & 1) * 8 + xcd;            // tile 0..15
  const int m0 = (t >> 2) * 128, n0 = (t & 3) * 128;
  const __bf16* A; const __bf16* B; __bf16* C; int ldc;
  if (z < 16) {
    const int b = z & 7, s = z >> 3;
    A = featb + (long)b * WE;
    B = qfkfT + (long)s * NE + (long)b * WE;
    C = (s ? kcat : qcat) + (long)b * CPL + 512;
    ldc = 1024;
  } else {
    const int b = z - 16;
    A = wb + 5 * WE;                          // Wfc (swapped operands -> vp2T)
    B = vpb + (long)b * WE;
    C = vp2T + (long)b * WE;
    ldc = 512;
  }
  f32x4 acc[4][4];
  #pragma unroll
  for (int i = 0; i < 4; ++i)
    #pragma unroll
    for (int j = 0; j < 4; ++j) acc[i][j] = 0.0f;
  nt_db<128, 128>(A, B, 512, m0, n0, smem, acc);

  const int tid = threadIdx.x, w = tid >> 6, l = tid & 63;
  const int quad = l >> 4, l16 = l & 15;
  const int wm = (w >> 1) * 64, wn = (w & 1) * 64;
  #pragma unroll
  for (int i = 0; i < 4; ++i) {
    const int mb = m0 + wm + i * 16 + quad * 4;
    #pragma unroll
    for (int j = 0; j < 4; ++j) {
      const int nn = n0 + wn + j * 16 + l16;
      f32x4 c = acc[i][j];
      #pragma unroll
      for (int r2 = 0; r2 < 4; ++r2)
        C[(long)(mb + r2) * ldc + nn] = (__bf16)c[r2];
    }
  }
}

// ======== k4: attn = tanh(mask(qcat.kcat^T/temp)), 64x64 tiles, 512 blocks ===
__global__ __launch_bounds__(256)
void scores_kernel(const __bf16* __restrict__ qcat, const __bf16* __restrict__ kcat,
                   const int* __restrict__ lens, float* __restrict__ attnf,
                   __bf16* __restrict__ attnb)
{
  __shared__ __align__(16) char smem[32768];  // 32 KB
  const int id = blockIdx.x;                  // 512 = 8 b * 64 tiles
  const int b = id & 7, g = id >> 3;          // one b per XCD -> L2-resident
  const int m0 = (g >> 3) * 64, n0 = (g & 7) * 64;
  const int len = lens[b];
  f32x4 acc[2][2];
  #pragma unroll
  for (int i = 0; i < 2; ++i)
    #pragma unroll
    for (int j = 0; j < 2; ++j) acc[i][j] = 0.0f;
  nt_db<64, 64>(qcat + (long)b * CPL, kcat + (long)b * CPL, 1024, m0, n0, smem, acc);

  const long off = (long)b * WE;
  const int tid = threadIdx.x, w = tid >> 6, l = tid & 63;
  const int quad = l >> 4, l16 = l & 15;
  const int wm = (w >> 1) * 32, wn = (w & 1) * 32;
  #pragma unroll
  for (int i = 0; i < 2; ++i) {
    const int mb = m0 + wm + i * 16 + quad * 4;
    #pragma unroll
    for (int j = 0; j < 2; ++j) {
      const int nn = n0 + wn + j * 16 + l16;
      f32x4 c = acc[i][j];
      #pragma unroll
      for (int r2 = 0; r2 < 4; ++r2) {
        float vv = c[r2] * INV_TEMP;
        vv = (nn < len) ? tanhf(vv) : 0.0f;
        attnf[off + (long)(mb + r2) * 512 + nn] = vv;
        attnb[off + (long)(mb + r2) * 512 + nn] = (__bf16)vv;
      }
    }
  }
}

// ======== k5: u = attn @ vp2 + q (residual), 64x64 tiles, 512 blocks ========
__global__ __launch_bounds__(256)
void av2_kernel(const __bf16* __restrict__ attnb, const __bf16* __restrict__ vp2T,
                const float* __restrict__ q, float* __restrict__ outp)
{
  __shared__ __align__(16) char smem[32768];
  const int id = blockIdx.x;
  const int b = id & 7, g = id >> 3;
  const int m0 = (g >> 3) * 64, n0 = (g & 7) * 64;
  f32x4 acc[2][2];
  #pragma unroll
  for (int i = 0; i < 2; ++i)
    #pragma unroll
    for (int j = 0; j < 2; ++j) acc[i][j] = 0.0f;
  nt_db<64, 64>(attnb + (long)b * WE, vp2T + (long)b * WE, 512, m0, n0, smem, acc);

  const int tid = threadIdx.x, w = tid >> 6, l = tid & 63;
  const int quad = l >> 4, l16 = l & 15;
  const int wm = (w >> 1) * 32, wn = (w & 1) * 32;
  #pragma unroll
  for (int i = 0; i < 2; ++i) {
    const int mb = m0 + wm + i * 16 + quad * 4;
    #pragma unroll
    for (int j = 0; j < 2; ++j) {
      const int nn = n0 + wn + j * 16 + l16;
      f32x4 c = acc[i][j];
      #pragma unroll
      for (int r2 = 0; r2 < 4; ++r2) {
        const long row = (long)b * 512 + mb + r2;
        outp[row * 512 + nn] = c[r2] + q[row * 512 + nn];
      }
    }
  }
}

// ======== k6: in-place row LayerNorm (1 wave per row) ========
__global__ __launch_bounds__(256)
void ln_kernel(float* __restrict__ o, const float* __restrict__ gamma,
               const float* __restrict__ beta)
{
  const int w = threadIdx.x >> 6, l = threadIdx.x & 63;
  float* p = o + ((long)blockIdx.x * 4 + w) * 512;
  const float4 a = ((const float4*)p)[l * 2];
  const float4 c = ((const float4*)p)[l * 2 + 1];
  float s  = a.x + a.y + a.z + a.w + c.x + c.y + c.z + c.w;
  float ss = a.x * a.x + a.y * a.y + a.z * a.z + a.w * a.w
           + c.x * c.x + c.y * c.y + c.z * c.z + c.w * c.w;
  #pragma unroll
  for (int o2 = 32; o2 >= 1; o2 >>= 1) { s += __shfl_xor(s, o2); ss += __shfl_xor(ss, o2); }
  const float mu = s * (1.0f / 512.0f);
  const float var = ss * (1.0f / 512.0f) - mu * mu;
  const float inv = 1.0f / sqrtf(var + 1e-6f);
  const float4 g0 = ((const float4*)gamma)[l * 2], g1 = ((const float4*)gamma)[l * 2 + 1];
  const float4 b0 = ((const float4*)beta)[l * 2],  b1 = ((const float4*)beta)[l * 2 + 1];
  float4 r0, r1;
  r0.x = (a.x - mu) * inv * g0.x + b0.x;
  r0.y = (a.y - mu) * inv * g0.y + b0.y;
  r0.z = (a.z - mu) * inv * g0.z + b0.z;
  r0.w = (a.w - mu) * inv * g0.w + b0.w;
  r1.x = (c.x - mu) * inv * g1.x + b1.x;
  r1.y = (c.y - mu) * inv * g1.y + b1.y;
  r1.z = (c.z - mu) * inv * g1.z + b1.z;
  r1.w = (c.w - mu) * inv * g1.w + b1.w;
  ((float4*)p)[l * 2] = r0;
  ((float4*)p)[l * 2 + 1] = r1;
}

extern "C" void kernel_launch(void* const* d_in, const int* in_sizes, int n_in,
                              void* d_out, int out_size, void* d_ws, size_t ws_size,
                              hipStream_t stream) {
    const float* q     = (const float*)d_in[0];
    const float* k     = (const float*)d_in[1];
    const float* v     = (const float*)d_in[2];
    const float* x     = (const float*)d_in[3];
    const int*   lens  = (const int*)d_in[4];
    const float* Wq    = (const float*)d_in[5];
    const float* Wk    = (const float*)d_in[6];
    const float* Wv    = (const float*)d_in[7];
    const float* Wqf   = (const float*)d_in[8];
    const float* Wkf   = (const float*)d_in[9];
    const float* Wfc   = (const float*)d_in[10];
    const float* imp   = (const float*)d_in[11];
    const float* gamma = (const float*)d_in[12];
    const float* beta  = (const float*)d_in[13];

    constexpr long MB = 1 << 20;
    char* w = (char*)d_ws;
    __bf16* qfkfT = (__bf16*)(w);            //  0.. 8MB : qfT,kfT (transposed)
    __bf16* vpb   = (__bf16*)(w + 8 * MB);   //  8..12MB : vp
    __bf16* vp2T  = (__bf16*)(w + 12 * MB);  // 12..16MB : vp2T
    __bf16* qcat  = (__bf16*)(w + 16 * MB);  // 16..24MB : [qp | qf2] K=1024
    __bf16* kcat  = (__bf16*)(w + 24 * MB);  // 24..32MB : [kp | kf2]
    __bf16* featb = (__bf16*)(w + 32 * MB);  // 32..36MB : feat_attn bf16
    __bf16* attnb = (__bf16*)(w + 36 * MB);  // 36..40MB : attn bf16

    float*  outp  = (float*)d_out;           // output 0 [B,L,D]
    float*  attnf = outp + NE;               // output 1 [B,L,L]

    // bf16 scratch in d_out: qb/kb (outp region) dead after k2; vb/wb (attnf
    // region) dead after k3; attnf written k4, outp written k5.
    __bf16* qb = (__bf16*)d_out;             //  0.. 4MB of d_out
    __bf16* kb = qb + NE;                    //  4.. 8MB
    __bf16* vb = kb + NE;                    //  8..12MB
    __bf16* wb = vb + NE;                    // 12..15MB : Wq,Wk,Wqf,Wkf,Wv,Wfc

    // 1) bf16 conversion of q,k,v + weights (896 blocks) + feature softmax (128)
    cvtfeat_kernel<<<dim3(1024), 256, 0, stream>>>(q, k, v, x, imp, lens,
                                                   Wq, Wk, Wqf, Wkf, Wv, Wfc,
                                                   qb, kb, vb, wb, featb);

    // 2) 5 projections, 128x128 counted-vmcnt core (640 blocks)
    proj_kernel<<<dim3(640), 256, 0, stream>>>(qb, kb, vb, wb,
                                               qcat, kcat, qfkfT, vpb);

    // 3) qf2,kf2 -> cat right halves + vp2T = NT(Wfc, vp) (384 blocks)
    mega2_kernel<<<dim3(384), 256, 0, stream>>>(featb, qfkfT, wb, vpb,
                                                qcat, kcat, vp2T);

    // 4) attn = tanh(mask(qcat.kcat^T / temp)), K=1024 (512 blocks, 64x64)
    scores_kernel<<<dim3(512), 256, 0, stream>>>(qcat, kcat, lens, attnf, attnb);

    // 5) u = attn @ vp2 + residual (512 blocks, 64x64)
    av2_kernel<<<dim3(512), 256, 0, stream>>>(attnb, vp2T, q, outp);

    // 6) in-place LayerNorm (1024 blocks, 1 wave/row)
    ln_kernel<<<dim3(1024), 256, 0, stream>>>(outp, gamma, beta);
}